// Round 1
// baseline (8073.195 us; speedup 1.0000x reference)
//
#include <hip/hip_runtime.h>
#include <math.h>

// Design notes (round 1, correctness-first fp32 baseline):
// - angle-block 2nd linear folded into inv W1: Wfa = W1[:,320:]@w2a, cfa = W1[:,320:]@b2a.
//   Stage s = silu(LN(cos*w1+b1)) as feat cols 320..383; add cfa to bias iff mask.
// - inv block fused: stage feat tile (16 edges) in LDS -> GEMM1 (K=384) -> LN+SiLU in regs
//   -> GEMM2 (384->128) -> atomicAdd scatter into node (d_out).
// - mrg block same structure, writes edge outputs directly.
// - ws usage < 10 MB: last_idx, mask, vn[E][4], Wfa, cfa. Everything rewritten every call.

#define TE   16     // edges per workgroup
#define SWP  20     // LDS W-slice row stride (floats): 16B-aligned, odd-ish banking
#define SFP  388    // inv feat row stride (floats), mult of 4 for float4
#define SFP2 324    // mrg feat row stride

__global__ void k_init(float* __restrict__ node_out, int n, int* __restrict__ last_idx) {
  int i = blockIdx.x * blockDim.x + threadIdx.x;
  if (i == 0) *last_idx = -1;
  for (; i < n; i += gridDim.x * blockDim.x) node_out[i] = 0.0f;
}

__global__ void k_mask(const int* __restrict__ src, const int* __restrict__ dst,
                       int E, int* __restrict__ mask, int* __restrict__ last_idx) {
  int i = blockIdx.x * blockDim.x + threadIdx.x;
  if (i >= E) return;
  int s0 = src[i], d0 = dst[i];
  int s1 = (i + 1 < E) ? src[i + 1] : 0;   // _shift semantics: pad 0
  int d1 = (i + 1 < E) ? dst[i + 1] : 0;
  int m = (s0 == s1) && (s0 != d0) && (s1 != d1);
  mask[i] = m;
  if (m) atomicMax(last_idx, i);
}

__global__ void k_vn(const float* __restrict__ ev, int E, int* __restrict__ mask,
                     const int* __restrict__ last_idx, float* __restrict__ vn) {
  int i = blockIdx.x * blockDim.x + threadIdx.x;
  if (i >= E) return;
  int m = mask[i] && (i != *last_idx);   // drop last true index (torch nonzero[:-1])
  mask[i] = m;
  float x = ev[3 * i], y = ev[3 * i + 1], z = ev[3 * i + 2];
  float invn = m ? (1.0f / sqrtf(x * x + y * y + z * z)) : 0.0f;
  vn[4 * i + 0] = x * invn;
  vn[4 * i + 1] = y * invn;
  vn[4 * i + 2] = z * invn;
  vn[4 * i + 3] = 0.0f;
}

__global__ void k_setup(const float* __restrict__ iw1, const float* __restrict__ aw2,
                        const float* __restrict__ ab2,
                        float* __restrict__ Wfa, float* __restrict__ cfa) {
  int n = blockIdx.x * blockDim.x + threadIdx.x;
  if (n < 384 * 64) {
    int r = n >> 6, j = n & 63;
    float acc = 0.0f;
    for (int k = 0; k < 64; ++k) acc += iw1[r * 384 + 320 + k] * aw2[k * 64 + j];
    Wfa[n] = acc;                       // Wfa[r*64+j]
  } else if (n < 384 * 64 + 384) {
    int r = n - 384 * 64;
    float acc = 0.0f;
    for (int k = 0; k < 64; ++k) acc += iw1[r * 384 + 320 + k] * ab2[k];
    cfa[r] = acc;
  }
}

__global__ __launch_bounds__(256, 2)
void k_inv(const float* __restrict__ atom, const float* __restrict__ el,
           const float* __restrict__ vn,
           const int* __restrict__ src, const int* __restrict__ dst,
           const int* __restrict__ mask,
           const float* __restrict__ aw1, const float* __restrict__ ab1,
           const float* __restrict__ ag,  const float* __restrict__ abn,
           const float* __restrict__ iw1, const float* __restrict__ ib1,
           const float* __restrict__ ig,  const float* __restrict__ ibn,
           const float* __restrict__ iw2, const float* __restrict__ ib2,
           const float* __restrict__ Wfa, const float* __restrict__ cfa,
           float* __restrict__ node_out, int E) {
  __shared__ __attribute__((aligned(16))) float sf[TE * SFP];   // 24832 B
  __shared__ __attribute__((aligned(16))) float sw[384 * SWP];  // 30720 B
  __shared__ int smask[TE], ssrc[TE], sdst[TE], sdsts[TE];

  const int t = threadIdx.x;
  const int rg = t & 31;
  const int eg = t >> 5;
  const int geb = blockIdx.x * TE;

  if (t < TE) {
    int ge = geb + t;
    int ok = (ge < E);
    smask[t] = ok ? mask[ge] : 0;
    ssrc[t]  = ok ? src[ge] : 0;
    sdst[t]  = ok ? dst[ge] : 0;
    sdsts[t] = (ge + 1 < E) ? dst[ge + 1] : 0;   // dst_s pads 0 -> atom row 0 (masked anyway)
  }
  __syncthreads();

  // ---- stage feat cols 0..319 (mask-zeroed rows) ----
  #pragma unroll
  for (int ii = 0; ii < 20; ++ii) {
    int l = t + 256 * ii;            // 0..5119 = 16 edges x 320 cols
    int e = l / 320, c = l % 320;
    int ge = geb + e;
    float v = 0.0f;
    if (ge < E && smask[e]) {
      if (c < 64)       v = atom[ssrc[e] * 64 + c];
      else if (c < 128) v = atom[sdst[e] * 64 + (c - 64)];
      else if (c < 192) v = el[(size_t)ge * 64 + (c - 128)];
      else if (c < 256) v = atom[sdsts[e] * 64 + (c - 192)];
      else              v = (ge + 1 < E) ? el[(size_t)(ge + 1) * 64 + (c - 256)] : 0.0f;
    }
    sf[e * SFP + c] = v;
  }

  // ---- angle hidden s -> feat cols 320..383 (one wave handles 4 edges) ----
  {
    int lane = t & 63, w = t >> 6;
    float w1v = aw1[lane], b1v = ab1[lane], gv = ag[lane], bnv = abn[lane];
    for (int q = 0; q < 4; ++q) {
      int e = w * 4 + q;
      int ge = geb + e;
      float cosv = 0.0f;
      if (ge < E) {
        float4 a = *(const float4*)(vn + 4 * (size_t)ge);
        float4 b = make_float4(0.f, 0.f, 0.f, 0.f);
        if (ge + 1 < E) b = *(const float4*)(vn + 4 * (size_t)(ge + 1));
        cosv = a.x * b.x + a.y * b.y + a.z * b.z;   // vn already mask-zeroed
      }
      float h = cosv * w1v + b1v;
      float s = h;
      for (int mm = 1; mm < 64; mm <<= 1) s += __shfl_xor(s, mm, 64);
      float mean = s * (1.0f / 64.0f);
      float d = h - mean;
      float vv = d * d;
      for (int mm = 1; mm < 64; mm <<= 1) vv += __shfl_xor(vv, mm, 64);
      float rstd = rsqrtf(vv * (1.0f / 64.0f) + 1e-6f);
      float hn = d * rstd * gv + bnv;
      float sv = hn / (1.0f + expf(-hn));
      sf[e * SFP + 320 + lane] = smask[e] ? sv : 0.0f;
    }
  }
  __syncthreads();

  // ---- GEMM1: H[16][384] = feat @ W1eff^T ; thread = 2 edges x 12 rows ----
  float acc[2][12];
  #pragma unroll
  for (int j = 0; j < 12; ++j) {
    int r = rg + 32 * j;
    float bv = ib1[r];
    float cf = cfa[r];
    acc[0][j] = bv + (smask[eg * 2 + 0] ? cf : 0.0f);
    acc[1][j] = bv + (smask[eg * 2 + 1] ? cf : 0.0f);
  }

  for (int kt = 0; kt < 24; ++kt) {
    int k0 = kt * 16;
    __syncthreads();
    #pragma unroll
    for (int ii = 0; ii < 24; ++ii) {
      int n = t + 256 * ii;          // 384 rows x 16 cols
      int row = n >> 4, c = n & 15;
      int cg = k0 + c;
      sw[row * SWP + c] = (cg < 320) ? iw1[row * 384 + cg] : Wfa[row * 64 + (cg - 320)];
    }
    __syncthreads();
    #pragma unroll
    for (int kk = 0; kk < 16; kk += 4) {
      float4 f0 = *(const float4*)(sf + (eg * 2 + 0) * SFP + k0 + kk);
      float4 f1 = *(const float4*)(sf + (eg * 2 + 1) * SFP + k0 + kk);
      #pragma unroll
      for (int j = 0; j < 12; ++j) {
        float4 wv = *(const float4*)(sw + (rg + 32 * j) * SWP + kk);
        acc[0][j] = fmaf(f0.x, wv.x, fmaf(f0.y, wv.y, fmaf(f0.z, wv.z, fmaf(f0.w, wv.w, acc[0][j]))));
        acc[1][j] = fmaf(f1.x, wv.x, fmaf(f1.y, wv.y, fmaf(f1.z, wv.z, fmaf(f1.w, wv.w, acc[1][j]))));
      }
    }
  }

  __syncthreads();
  // ---- LayerNorm(384) + SiLU -> write Hn back into sf ----
  {
    float gvals[12], bnvals[12];
    #pragma unroll
    for (int j = 0; j < 12; ++j) { int r = rg + 32 * j; gvals[j] = ig[r]; bnvals[j] = ibn[r]; }
    #pragma unroll
    for (int i = 0; i < 2; ++i) {
      float s = 0.0f, q = 0.0f;
      #pragma unroll
      for (int j = 0; j < 12; ++j) { float v = acc[i][j]; s += v; q += v * v; }
      for (int mm = 1; mm < 32; mm <<= 1) { s += __shfl_xor(s, mm, 32); q += __shfl_xor(q, mm, 32); }
      float mean = s * (1.0f / 384.0f);
      float var  = q * (1.0f / 384.0f) - mean * mean;
      float rstd = rsqrtf(var + 1e-6f);
      #pragma unroll
      for (int j = 0; j < 12; ++j) {
        float hn = (acc[i][j] - mean) * rstd * gvals[j] + bnvals[j];
        float sv = hn / (1.0f + expf(-hn));
        sf[(eg * 2 + i) * SFP + rg + 32 * j] = sv;
      }
    }
  }
  __syncthreads();

  // ---- GEMM2: Z[16][128] = Hn @ W2^T ; thread = 2 edges x 4 rows ----
  float acc2[2][4];
  #pragma unroll
  for (int j = 0; j < 4; ++j) {
    float bv = ib2[rg + 32 * j];
    acc2[0][j] = bv; acc2[1][j] = bv;
  }

  for (int kt = 0; kt < 24; ++kt) {
    int k0 = kt * 16;
    __syncthreads();
    #pragma unroll
    for (int ii = 0; ii < 8; ++ii) {
      int n = t + 256 * ii;          // 128 rows x 16 cols
      int row = n >> 4, c = n & 15;
      sw[row * SWP + c] = iw2[row * 384 + k0 + c];
    }
    __syncthreads();
    #pragma unroll
    for (int kk = 0; kk < 16; kk += 4) {
      float4 f0 = *(const float4*)(sf + (eg * 2 + 0) * SFP + k0 + kk);
      float4 f1 = *(const float4*)(sf + (eg * 2 + 1) * SFP + k0 + kk);
      #pragma unroll
      for (int j = 0; j < 4; ++j) {
        float4 wv = *(const float4*)(sw + (rg + 32 * j) * SWP + kk);
        acc2[0][j] = fmaf(f0.x, wv.x, fmaf(f0.y, wv.y, fmaf(f0.z, wv.z, fmaf(f0.w, wv.w, acc2[0][j]))));
        acc2[1][j] = fmaf(f1.x, wv.x, fmaf(f1.y, wv.y, fmaf(f1.z, wv.z, fmaf(f1.w, wv.w, acc2[1][j]))));
      }
    }
  }

  // ---- scatter: node[dst] += Z ----
  #pragma unroll
  for (int i = 0; i < 2; ++i) {
    int e = eg * 2 + i, ge = geb + e;
    if (ge < E) {
      float* np = node_out + (size_t)sdst[e] * 128;
      #pragma unroll
      for (int j = 0; j < 4; ++j)
        atomicAdd(np + rg + 32 * j, acc2[i][j]);
    }
  }
}

__global__ __launch_bounds__(256, 2)
void k_mrg(const float* __restrict__ node, const float* __restrict__ el,
           const int* __restrict__ src, const int* __restrict__ dst,
           const float* __restrict__ mw1, const float* __restrict__ mb1,
           const float* __restrict__ mg,  const float* __restrict__ mbn,
           const float* __restrict__ mw2, const float* __restrict__ mb2,
           float* __restrict__ edge_out, int E) {
  __shared__ __attribute__((aligned(16))) float sf[TE * SFP2];  // 20736 B
  __shared__ __attribute__((aligned(16))) float sw[128 * SWP];  // 10240 B
  __shared__ int ssrc[TE], sdst[TE];

  const int t = threadIdx.x;
  const int rg = t & 31, eg = t >> 5;
  const int geb = blockIdx.x * TE;

  if (t < TE) {
    int ge = geb + t;
    int ok = ge < E;
    ssrc[t] = ok ? src[ge] : 0;
    sdst[t] = ok ? dst[ge] : 0;
  }
  __syncthreads();

  #pragma unroll
  for (int ii = 0; ii < 20; ++ii) {
    int l = t + 256 * ii;            // 16 edges x 320 cols
    int e = l / 320, c = l % 320;
    int ge = geb + e;
    float v = 0.0f;
    if (ge < E) {
      if (c < 128)      v = node[(size_t)ssrc[e] * 128 + c];
      else if (c < 256) v = node[(size_t)sdst[e] * 128 + (c - 128)];
      else              v = el[(size_t)ge * 64 + (c - 256)];
    }
    sf[e * SFP2 + c] = v;
  }
  __syncthreads();

  float acc[2][4];
  #pragma unroll
  for (int j = 0; j < 4; ++j) {
    float bv = mb1[rg + 32 * j];
    acc[0][j] = bv; acc[1][j] = bv;
  }

  for (int kt = 0; kt < 20; ++kt) {   // K = 320
    int k0 = kt * 16;
    __syncthreads();
    #pragma unroll
    for (int ii = 0; ii < 8; ++ii) {
      int n = t + 256 * ii;
      int row = n >> 4, c = n & 15;
      sw[row * SWP + c] = mw1[row * 320 + k0 + c];
    }
    __syncthreads();
    #pragma unroll
    for (int kk = 0; kk < 16; kk += 4) {
      float4 f0 = *(const float4*)(sf + (eg * 2 + 0) * SFP2 + k0 + kk);
      float4 f1 = *(const float4*)(sf + (eg * 2 + 1) * SFP2 + k0 + kk);
      #pragma unroll
      for (int j = 0; j < 4; ++j) {
        float4 wv = *(const float4*)(sw + (rg + 32 * j) * SWP + kk);
        acc[0][j] = fmaf(f0.x, wv.x, fmaf(f0.y, wv.y, fmaf(f0.z, wv.z, fmaf(f0.w, wv.w, acc[0][j]))));
        acc[1][j] = fmaf(f1.x, wv.x, fmaf(f1.y, wv.y, fmaf(f1.z, wv.z, fmaf(f1.w, wv.w, acc[1][j]))));
      }
    }
  }

  __syncthreads();
  {
    float gvals[4], bnvals[4];
    #pragma unroll
    for (int j = 0; j < 4; ++j) { int r = rg + 32 * j; gvals[j] = mg[r]; bnvals[j] = mbn[r]; }
    #pragma unroll
    for (int i = 0; i < 2; ++i) {
      float s = 0.0f, q = 0.0f;
      #pragma unroll
      for (int j = 0; j < 4; ++j) { float v = acc[i][j]; s += v; q += v * v; }
      for (int mm = 1; mm < 32; mm <<= 1) { s += __shfl_xor(s, mm, 32); q += __shfl_xor(q, mm, 32); }
      float mean = s * (1.0f / 128.0f);
      float var  = q * (1.0f / 128.0f) - mean * mean;
      float rstd = rsqrtf(var + 1e-6f);
      #pragma unroll
      for (int j = 0; j < 4; ++j) {
        float hn = (acc[i][j] - mean) * rstd * gvals[j] + bnvals[j];
        float sv = hn / (1.0f + expf(-hn));
        sf[(eg * 2 + i) * SFP2 + rg + 32 * j] = sv;
      }
    }
  }
  __syncthreads();

  float acc2[2][4];
  #pragma unroll
  for (int j = 0; j < 4; ++j) {
    float bv = mb2[rg + 32 * j];
    acc2[0][j] = bv; acc2[1][j] = bv;
  }

  for (int kt = 0; kt < 8; ++kt) {    // K = 128
    int k0 = kt * 16;
    __syncthreads();
    #pragma unroll
    for (int ii = 0; ii < 8; ++ii) {
      int n = t + 256 * ii;
      int row = n >> 4, c = n & 15;
      sw[row * SWP + c] = mw2[row * 128 + k0 + c];
    }
    __syncthreads();
    #pragma unroll
    for (int kk = 0; kk < 16; kk += 4) {
      float4 f0 = *(const float4*)(sf + (eg * 2 + 0) * SFP2 + k0 + kk);
      float4 f1 = *(const float4*)(sf + (eg * 2 + 1) * SFP2 + k0 + kk);
      #pragma unroll
      for (int j = 0; j < 4; ++j) {
        float4 wv = *(const float4*)(sw + (rg + 32 * j) * SWP + kk);
        acc2[0][j] = fmaf(f0.x, wv.x, fmaf(f0.y, wv.y, fmaf(f0.z, wv.z, fmaf(f0.w, wv.w, acc2[0][j]))));
        acc2[1][j] = fmaf(f1.x, wv.x, fmaf(f1.y, wv.y, fmaf(f1.z, wv.z, fmaf(f1.w, wv.w, acc2[1][j]))));
      }
    }
  }

  #pragma unroll
  for (int i = 0; i < 2; ++i) {
    int ge = geb + eg * 2 + i;
    if (ge < E) {
      #pragma unroll
      for (int j = 0; j < 4; ++j)
        edge_out[(size_t)ge * 128 + rg + 32 * j] = acc2[i][j];
    }
  }
}

extern "C" void kernel_launch(void* const* d_in, const int* in_sizes, int n_in,
                              void* d_out, int out_size, void* d_ws, size_t ws_size,
                              hipStream_t stream) {
  const float* atom = (const float*)d_in[0];
  const float* el   = (const float*)d_in[1];
  const float* ev   = (const float*)d_in[2];
  const int*   eidx = (const int*)d_in[3];
  const float* aw1  = (const float*)d_in[4];
  const float* ab1  = (const float*)d_in[5];
  const float* ag   = (const float*)d_in[6];
  const float* abn  = (const float*)d_in[7];
  const float* aw2  = (const float*)d_in[8];
  const float* ab2  = (const float*)d_in[9];
  const float* iw1  = (const float*)d_in[10];
  const float* ib1  = (const float*)d_in[11];
  const float* ig   = (const float*)d_in[12];
  const float* ibn  = (const float*)d_in[13];
  const float* iw2  = (const float*)d_in[14];
  const float* ib2  = (const float*)d_in[15];
  const float* mw1  = (const float*)d_in[16];
  const float* mb1  = (const float*)d_in[17];
  const float* mg   = (const float*)d_in[18];
  const float* mbn  = (const float*)d_in[19];
  const float* mw2  = (const float*)d_in[20];
  const float* mb2  = (const float*)d_in[21];

  const int N = in_sizes[0] / 64;
  const int E = in_sizes[1] / 64;
  const int* src = eidx;
  const int* dst = eidx + E;

  char* ws = (char*)d_ws;
  size_t off = 0;
  int* last_idx = (int*)(ws + off); off += 512;
  int* maskp    = (int*)(ws + off); off += ((size_t)E * 4 + 511) & ~(size_t)511;
  float* vn     = (float*)(ws + off); off += ((size_t)E * 16 + 511) & ~(size_t)511;
  float* Wfa    = (float*)(ws + off); off += (size_t)384 * 64 * 4;
  float* cfa    = (float*)(ws + off); off += 512;

  float* node_out = (float*)d_out;
  float* edge_out = node_out + (size_t)N * 128;

  const int eb = (E + 255) / 256;
  const int tb = (E + TE - 1) / TE;

  k_init<<<4096, 256, 0, stream>>>(node_out, N * 128, last_idx);
  k_mask<<<eb, 256, 0, stream>>>(src, dst, E, maskp, last_idx);
  k_vn<<<eb, 256, 0, stream>>>(ev, E, maskp, last_idx, vn);
  k_setup<<<(384 * 64 + 384 + 255) / 256, 256, 0, stream>>>(iw1, aw2, ab2, Wfa, cfa);
  k_inv<<<tb, 256, 0, stream>>>(atom, el, vn, src, dst, maskp,
                                aw1, ab1, ag, abn,
                                iw1, ib1, ig, ibn, iw2, ib2,
                                Wfa, cfa, node_out, E);
  k_mrg<<<tb, 256, 0, stream>>>(node_out, el, src, dst,
                                mw1, mb1, mg, mbn, mw2, mb2,
                                edge_out, E);
}

// Round 2
// 1149.680 us; speedup vs baseline: 7.0221x; 7.0221x over previous
//
#include <hip/hip_runtime.h>
#include <math.h>

// Round 2: bf16 MFMA rewrite.
// - 64 edges/block, 4 waves x 16-edge m-tile, mfma_f32_16x16x32_bf16.
// - B-operands pre-swizzled (k_swz) into fragment order: one coalesced 16B/lane load per MFMA.
// - feat/H in LDS bf16, stride 392/328 ushorts (2-way bank aliasing = free).
// - angle block fully folded: closed-form LN of affine-in-cos + Wfa/cfa fold into inv W1.
// - LN stats in fp32 from accumulators, intra-quad shfl_xor reduction.

typedef short short8 __attribute__((ext_vector_type(8)));
typedef float f32x4 __attribute__((ext_vector_type(4)));

#define SFA 392   // k_inv feat row stride (ushorts); 392*2=784B, 784/4=196 dwords, 196%32=4 -> 2-way
#define SFB 328   // k_mrg feat row stride (ushorts); 656B -> 164 dwords, 164%32=4 -> 2-way

__device__ __forceinline__ unsigned short f2bf(float x) {
  union { float f; unsigned u; } v; v.f = x;
  unsigned r = (v.u + 0x7FFFu + ((v.u >> 16) & 1u)) >> 16;
  return (unsigned short)r;
}
__device__ __forceinline__ float bf2f(unsigned short h) {
  union { unsigned u; float f; } v; v.u = ((unsigned)h) << 16;
  return v.f;
}
__device__ __forceinline__ float silu_f(float x) { return x / (1.0f + __expf(-x)); }

__global__ void k_init(float* __restrict__ node_out, int n, int* __restrict__ last_idx) {
  int i = blockIdx.x * blockDim.x + threadIdx.x;
  if (i == 0) *last_idx = -1;
  for (; i < n; i += gridDim.x * blockDim.x) node_out[i] = 0.0f;
}

__global__ void k_mask(const int* __restrict__ src, const int* __restrict__ dst,
                       int E, unsigned char* __restrict__ rawmask, int* __restrict__ last_idx) {
  int i = blockIdx.x * blockDim.x + threadIdx.x;
  if (i >= E) return;
  int s0 = src[i], d0 = dst[i];
  int s1 = (i + 1 < E) ? src[i + 1] : 0;   // _shift pads 0
  int d1 = (i + 1 < E) ? dst[i + 1] : 0;
  int m = (s0 == s1) && (s0 != d0) && (s1 != d1);
  rawmask[i] = (unsigned char)m;
  if (m) atomicMax(last_idx, i);
}

// Wfa = iw1[:,320:]@aw2 ; cfa = iw1[:,320:]@ab2 ; angle closed-form LN folds.
__global__ void k_setup(const float* __restrict__ iw1, const float* __restrict__ aw2,
                        const float* __restrict__ ab2,
                        const float* __restrict__ aw1, const float* __restrict__ ab1,
                        const float* __restrict__ ag,
                        float* __restrict__ Wfa, float* __restrict__ cfa,
                        float* __restrict__ wg, float* __restrict__ bg,
                        float* __restrict__ angp) {
  int n = blockIdx.x * blockDim.x + threadIdx.x;
  if (n < 384 * 64) {
    int r = n >> 6, j = n & 63;
    float acc = 0.0f;
    for (int k = 0; k < 64; ++k) acc += iw1[r * 384 + 320 + k] * aw2[k * 64 + j];
    Wfa[n] = acc;
  } else if (n < 384 * 64 + 384) {
    int r = n - 384 * 64;
    float acc = 0.0f;
    for (int k = 0; k < 64; ++k) acc += iw1[r * 384 + 320 + k] * ab2[k];
    cfa[r] = acc;
  } else if (n < 384 * 64 + 384 + 64) {
    int j = n - (384 * 64 + 384);
    float wm = 0.f, bm = 0.f;
    for (int k = 0; k < 64; ++k) { wm += aw1[k]; bm += ab1[k]; }
    wm *= (1.f / 64.f); bm *= (1.f / 64.f);
    wg[j] = (aw1[j] - wm) * ag[j];
    bg[j] = (ab1[j] - bm) * ag[j];
    if (j == 0) {
      float vw = 0.f, cwb = 0.f, vb = 0.f;
      for (int k = 0; k < 64; ++k) {
        float dw = aw1[k] - wm, db = ab1[k] - bm;
        vw += dw * dw; cwb += dw * db; vb += db * db;
      }
      angp[0] = vw * (1.f / 64.f);
      angp[1] = cwb * (1.f / 64.f);
      angp[2] = vb * (1.f / 64.f);
    }
  }
}

// Swizzle weights into B-fragment order: B[(nt*KT+kt)*64 + lane][8] with
// value = W[n = nt*16 + (lane&15)][k = kt*32 + ((lane>>4)&3)*8 + j]  (bf16).
__global__ void k_swz(const float* __restrict__ iw1, const float* __restrict__ iw2,
                      const float* __restrict__ mw1, const float* __restrict__ mw2,
                      const float* __restrict__ Wfa,
                      unsigned short* __restrict__ B1, unsigned short* __restrict__ B2,
                      unsigned short* __restrict__ B3, unsigned short* __restrict__ B4) {
  const int NC1 = 24 * 12 * 64, NC2 = 8 * 12 * 64, NC3 = 8 * 10 * 64, NC4 = 8 * 4 * 64;
  int cid = blockIdx.x * blockDim.x + threadIdx.x;
  int region, rel, KT;
  unsigned short* out;
  if (cid < NC1)                    { region = 1; rel = cid;                KT = 12; out = B1; }
  else if (cid < NC1 + NC2)         { region = 2; rel = cid - NC1;          KT = 12; out = B2; }
  else if (cid < NC1 + NC2 + NC3)   { region = 3; rel = cid - NC1 - NC2;    KT = 10; out = B3; }
  else if (cid < NC1 + NC2 + NC3 + NC4) { region = 4; rel = cid - NC1 - NC2 - NC3; KT = 4; out = B4; }
  else return;
  int l = rel & 63;
  int ktn = rel >> 6;
  int kt = ktn % KT, nt = ktn / KT;
  int n = nt * 16 + (l & 15);
  int k0 = kt * 32 + ((l >> 4) & 3) * 8;
  short8 pk;
  #pragma unroll
  for (int j = 0; j < 8; ++j) {
    int k = k0 + j;
    float v;
    if (region == 1)      v = (k < 320) ? iw1[n * 384 + k] : Wfa[n * 64 + (k - 320)];
    else if (region == 2) v = iw2[n * 384 + k];
    else if (region == 3) v = mw1[n * 320 + k];
    else                  v = mw2[n * 128 + k];
    pk[j] = (short)f2bf(v);
  }
  *(short8*)(out + ((size_t)rel << 3)) = pk;
}

__global__ __launch_bounds__(256, 3)
void k_inv(const float* __restrict__ atom, const float* __restrict__ el,
           const float* __restrict__ ev,
           const int* __restrict__ src, const int* __restrict__ dst,
           const unsigned char* __restrict__ rawmask, const int* __restrict__ last_idx,
           const float* __restrict__ ib1, const float* __restrict__ ig,
           const float* __restrict__ ibn, const float* __restrict__ ib2,
           const float* __restrict__ cfa, const float* __restrict__ wg,
           const float* __restrict__ bg, const float* __restrict__ abn,
           const float* __restrict__ angp,
           const unsigned short* __restrict__ Bsw1, const unsigned short* __restrict__ Bsw2,
           float* __restrict__ node_out, int E) {
  __shared__ __attribute__((aligned(16))) unsigned short sf[64 * SFA];  // 50176 B
  __shared__ float scos[64], srr[64], smaskf[64], smean[64], srstd[64];
  __shared__ int ssrc[64], sdst[64], sdsts[64];

  const int t = threadIdx.x;
  const int lane = t & 63;
  const int q = (lane >> 4) & 3;
  const int col = lane & 15;
  const int mbase = (t >> 6) * 16;
  const int geb = blockIdx.x * 64;

  // ---- pre-pass: per-edge mask, indices, cos, closed-form LN rstd ----
  if (t < 64) {
    int e = t, ge = geb + e;
    int last = *last_idx;
    int ok = ge < E;
    int m0 = 0, m1 = 0, s0 = 0, d0 = 0, d1 = 0;
    if (ok) { s0 = src[ge]; d0 = dst[ge]; m0 = rawmask[ge] && (ge != last); }
    if (ge + 1 < E) { d1 = dst[ge + 1]; m1 = rawmask[ge + 1] && (ge + 1 != last); }
    ssrc[e] = s0; sdst[e] = d0; sdsts[e] = d1;
    smaskf[e] = m0 ? 1.0f : 0.0f;
    float cosv = 0.f;
    if (m0 && m1) {
      float ax = ev[3 * ge], ay = ev[3 * ge + 1], az = ev[3 * ge + 2];
      float bx = ev[3 * ge + 3], by = ev[3 * ge + 4], bz = ev[3 * ge + 5];
      cosv = (ax * bx + ay * by + az * bz) *
             rsqrtf((ax * ax + ay * ay + az * az) * (bx * bx + by * by + bz * bz));
    }
    scos[e] = cosv;
    srr[e] = rsqrtf(cosv * cosv * angp[0] + 2.f * cosv * angp[1] + angp[2] + 1e-6f);
  }
  __syncthreads();

  // ---- stage feat [64][384] bf16 into LDS (mask-zeroed; angle cols closed-form) ----
  #pragma unroll
  for (int ii = 0; ii < 12; ++ii) {
    int cid = t + 256 * ii;          // 3072 chunks of 8
    int e = cid / 48, c0 = (cid % 48) * 8;
    int ge = geb + e;
    float mk = smaskf[e];
    float v[8];
    if (c0 < 320) {
      const float* sp;
      if (c0 < 64)        sp = atom + (size_t)ssrc[e] * 64 + c0;
      else if (c0 < 128)  sp = atom + (size_t)sdst[e] * 64 + (c0 - 64);
      else if (c0 < 192)  sp = el + (size_t)ge * 64 + (c0 - 128);
      else if (c0 < 256)  sp = atom + (size_t)sdsts[e] * 64 + (c0 - 192);
      else                sp = el + (size_t)(ge + 1) * 64 + (c0 - 256);
      bool ld = (ge < E) && (mk > 0.f) && !(c0 >= 256 && ge + 1 >= E);
      if (ld) {
        float4 p0 = *(const float4*)sp;
        float4 p1 = *(const float4*)(sp + 4);
        v[0] = p0.x; v[1] = p0.y; v[2] = p0.z; v[3] = p0.w;
        v[4] = p1.x; v[5] = p1.y; v[6] = p1.z; v[7] = p1.w;
      } else {
        #pragma unroll
        for (int j = 0; j < 8; ++j) v[j] = 0.f;
      }
    } else {
      int j0 = c0 - 320;
      float cosv = scos[e], rr = srr[e];
      float4 w0 = *(const float4*)(wg + j0),  w1 = *(const float4*)(wg + j0 + 4);
      float4 g0 = *(const float4*)(bg + j0),  g1 = *(const float4*)(bg + j0 + 4);
      float4 n0 = *(const float4*)(abn + j0), n1 = *(const float4*)(abn + j0 + 4);
      float W[8]  = {w0.x, w0.y, w0.z, w0.w, w1.x, w1.y, w1.z, w1.w};
      float G[8]  = {g0.x, g0.y, g0.z, g0.w, g1.x, g1.y, g1.z, g1.w};
      float Bn[8] = {n0.x, n0.y, n0.z, n0.w, n1.x, n1.y, n1.z, n1.w};
      #pragma unroll
      for (int j = 0; j < 8; ++j) {
        float hn = (cosv * W[j] + G[j]) * rr + Bn[j];
        v[j] = mk * silu_f(hn);
      }
    }
    short8 pk;
    #pragma unroll
    for (int j = 0; j < 8; ++j) pk[j] = (short)f2bf(v[j]);
    *(short8*)(sf + e * SFA + c0) = pk;
  }
  __syncthreads();

  // ---- GEMM1: H[16x384] = feat @ W1eff^T, per wave ----
  short8 af[12];
  #pragma unroll
  for (int kt = 0; kt < 12; ++kt)
    af[kt] = *(const short8*)(sf + (mbase + col) * SFA + kt * 32 + q * 8);

  float mrow[4]; int drow[4];
  #pragma unroll
  for (int r = 0; r < 4; ++r) {
    int e = mbase + q * 4 + r;
    mrow[r] = smaskf[e];
    drow[r] = sdst[e];
  }

  float sums[4] = {0, 0, 0, 0}, sqs[4] = {0, 0, 0, 0};
  for (int nt = 0; nt < 24; ++nt) {
    int n = nt * 16 + col;
    float biasv = ib1[n], cfav = cfa[n];
    short8 bf[12];
    #pragma unroll
    for (int kt = 0; kt < 12; ++kt)
      bf[kt] = *(const short8*)(Bsw1 + (((nt * 12 + kt) * 64 + lane) << 3));
    f32x4 acc;
    #pragma unroll
    for (int r = 0; r < 4; ++r) acc[r] = biasv + mrow[r] * cfav;
    #pragma unroll
    for (int kt = 0; kt < 12; ++kt)
      acc = __builtin_amdgcn_mfma_f32_16x16x32_bf16(af[kt], bf[kt], acc, 0, 0, 0);
    #pragma unroll
    for (int r = 0; r < 4; ++r) {
      float vv = acc[r];
      sums[r] += vv; sqs[r] += vv * vv;
      sf[(mbase + q * 4 + r) * SFA + nt * 16 + col] = f2bf(vv);   // C-layout -> LDS
    }
  }

  // intra-quad (16-lane) reduction for per-edge LN stats
  #pragma unroll
  for (int r = 0; r < 4; ++r) {
    float s = sums[r], ss = sqs[r];
    for (int m = 1; m < 16; m <<= 1) { s += __shfl_xor(s, m, 64); ss += __shfl_xor(ss, m, 64); }
    sums[r] = s; sqs[r] = ss;
  }
  if (col == 0) {
    #pragma unroll
    for (int r = 0; r < 4; ++r) {
      float mean = sums[r] * (1.f / 384.f);
      float var = sqs[r] * (1.f / 384.f) - mean * mean;
      smean[mbase + q * 4 + r] = mean;
      srstd[mbase + q * 4 + r] = rsqrtf(var + 1e-6f);
    }
  }
  __syncthreads();

  // ---- GEMM2: Z[16x128] = silu(LN(H)) @ W2^T ; normalize-on-load A' frags ----
  short8 af2[12];
  {
    int e = mbase + col;
    float mean = smean[e], rstd = srstd[e];
    #pragma unroll
    for (int kt = 0; kt < 12; ++kt) {
      int kb = kt * 32 + q * 8;
      short8 h8 = *(const short8*)(sf + e * SFA + kb);
      float4 g0 = *(const float4*)(ig + kb),  g1 = *(const float4*)(ig + kb + 4);
      float4 b0 = *(const float4*)(ibn + kb), b1v = *(const float4*)(ibn + kb + 4);
      float G[8] = {g0.x, g0.y, g0.z, g0.w, g1.x, g1.y, g1.z, g1.w};
      float B[8] = {b0.x, b0.y, b0.z, b0.w, b1v.x, b1v.y, b1v.z, b1v.w};
      short8 pk;
      #pragma unroll
      for (int j = 0; j < 8; ++j) {
        float h = bf2f((unsigned short)h8[j]);
        float hn = (h - mean) * rstd * G[j] + B[j];
        pk[j] = (short)f2bf(silu_f(hn));
      }
      af2[kt] = pk;
    }
  }
  for (int nt = 0; nt < 8; ++nt) {
    int n = nt * 16 + col;
    float biasv = ib2[n];
    short8 bf[12];
    #pragma unroll
    for (int kt = 0; kt < 12; ++kt)
      bf[kt] = *(const short8*)(Bsw2 + (((nt * 12 + kt) * 64 + lane) << 3));
    f32x4 acc;
    #pragma unroll
    for (int r = 0; r < 4; ++r) acc[r] = biasv;
    #pragma unroll
    for (int kt = 0; kt < 12; ++kt)
      acc = __builtin_amdgcn_mfma_f32_16x16x32_bf16(af2[kt], bf[kt], acc, 0, 0, 0);
    #pragma unroll
    for (int r = 0; r < 4; ++r) {
      int ge = geb + mbase + q * 4 + r;
      if (ge < E) atomicAdd(node_out + (size_t)drow[r] * 128 + n, acc[r]);
    }
  }
}

__global__ __launch_bounds__(256, 3)
void k_mrg(const float* __restrict__ node, const float* __restrict__ el,
           const int* __restrict__ src, const int* __restrict__ dst,
           const float* __restrict__ mb1, const float* __restrict__ mg,
           const float* __restrict__ mbn, const float* __restrict__ mb2,
           const unsigned short* __restrict__ Bsw3, const unsigned short* __restrict__ Bsw4,
           float* __restrict__ edge_out, int E) {
  __shared__ __attribute__((aligned(16))) unsigned short sf[64 * SFB];  // 41984 B
  __shared__ float smean[64], srstd[64];
  __shared__ int ssrc[64], sdst[64];

  const int t = threadIdx.x;
  const int lane = t & 63;
  const int q = (lane >> 4) & 3;
  const int col = lane & 15;
  const int mbase = (t >> 6) * 16;
  const int geb = blockIdx.x * 64;

  if (t < 64) {
    int ge = geb + t;
    int ok = ge < E;
    ssrc[t] = ok ? src[ge] : 0;
    sdst[t] = ok ? dst[ge] : 0;
  }
  __syncthreads();

  // stage [64][320]: node[src] | node[dst] | el
  #pragma unroll
  for (int ii = 0; ii < 10; ++ii) {
    int cid = t + 256 * ii;          // 2560 chunks
    int e = cid / 40, c0 = (cid % 40) * 8;
    int ge = geb + e;
    float v[8];
    const float* sp;
    if (c0 < 128)       sp = node + (size_t)ssrc[e] * 128 + c0;
    else if (c0 < 256)  sp = node + (size_t)sdst[e] * 128 + (c0 - 128);
    else                sp = el + (size_t)ge * 64 + (c0 - 256);
    if (ge < E) {
      float4 p0 = *(const float4*)sp;
      float4 p1 = *(const float4*)(sp + 4);
      v[0] = p0.x; v[1] = p0.y; v[2] = p0.z; v[3] = p0.w;
      v[4] = p1.x; v[5] = p1.y; v[6] = p1.z; v[7] = p1.w;
    } else {
      #pragma unroll
      for (int j = 0; j < 8; ++j) v[j] = 0.f;
    }
    short8 pk;
    #pragma unroll
    for (int j = 0; j < 8; ++j) pk[j] = (short)f2bf(v[j]);
    *(short8*)(sf + e * SFB + c0) = pk;
  }
  __syncthreads();

  // GEMM1: K=320 (10 kt), N=128 (8 nt)
  short8 af[10];
  #pragma unroll
  for (int kt = 0; kt < 10; ++kt)
    af[kt] = *(const short8*)(sf + (mbase + col) * SFB + kt * 32 + q * 8);

  float sums[4] = {0, 0, 0, 0}, sqs[4] = {0, 0, 0, 0};
  for (int nt = 0; nt < 8; ++nt) {
    int n = nt * 16 + col;
    float biasv = mb1[n];
    short8 bf[10];
    #pragma unroll
    for (int kt = 0; kt < 10; ++kt)
      bf[kt] = *(const short8*)(Bsw3 + (((nt * 10 + kt) * 64 + lane) << 3));
    f32x4 acc;
    #pragma unroll
    for (int r = 0; r < 4; ++r) acc[r] = biasv;
    #pragma unroll
    for (int kt = 0; kt < 10; ++kt)
      acc = __builtin_amdgcn_mfma_f32_16x16x32_bf16(af[kt], bf[kt], acc, 0, 0, 0);
    #pragma unroll
    for (int r = 0; r < 4; ++r) {
      float vv = acc[r];
      sums[r] += vv; sqs[r] += vv * vv;
      sf[(mbase + q * 4 + r) * SFB + nt * 16 + col] = f2bf(vv);
    }
  }

  #pragma unroll
  for (int r = 0; r < 4; ++r) {
    float s = sums[r], ss = sqs[r];
    for (int m = 1; m < 16; m <<= 1) { s += __shfl_xor(s, m, 64); ss += __shfl_xor(ss, m, 64); }
    sums[r] = s; sqs[r] = ss;
  }
  if (col == 0) {
    #pragma unroll
    for (int r = 0; r < 4; ++r) {
      float mean = sums[r] * (1.f / 128.f);
      float var = sqs[r] * (1.f / 128.f) - mean * mean;
      smean[mbase + q * 4 + r] = mean;
      srstd[mbase + q * 4 + r] = rsqrtf(var + 1e-6f);
    }
  }
  __syncthreads();

  // GEMM2: K=128 (4 kt), N=128 (8 nt)
  short8 af2[4];
  {
    int e = mbase + col;
    float mean = smean[e], rstd = srstd[e];
    #pragma unroll
    for (int kt = 0; kt < 4; ++kt) {
      int kb = kt * 32 + q * 8;
      short8 h8 = *(const short8*)(sf + e * SFB + kb);
      float4 g0 = *(const float4*)(mg + kb),  g1 = *(const float4*)(mg + kb + 4);
      float4 b0 = *(const float4*)(mbn + kb), b1v = *(const float4*)(mbn + kb + 4);
      float G[8] = {g0.x, g0.y, g0.z, g0.w, g1.x, g1.y, g1.z, g1.w};
      float B[8] = {b0.x, b0.y, b0.z, b0.w, b1v.x, b1v.y, b1v.z, b1v.w};
      short8 pk;
      #pragma unroll
      for (int j = 0; j < 8; ++j) {
        float h = bf2f((unsigned short)h8[j]);
        float hn = (h - mean) * rstd * G[j] + B[j];
        pk[j] = (short)f2bf(silu_f(hn));
      }
      af2[kt] = pk;
    }
  }
  for (int nt = 0; nt < 8; ++nt) {
    int n = nt * 16 + col;
    float biasv = mb2[n];
    short8 bf[4];
    #pragma unroll
    for (int kt = 0; kt < 4; ++kt)
      bf[kt] = *(const short8*)(Bsw4 + (((nt * 4 + kt) * 64 + lane) << 3));
    f32x4 acc;
    #pragma unroll
    for (int r = 0; r < 4; ++r) acc[r] = biasv;
    #pragma unroll
    for (int kt = 0; kt < 4; ++kt)
      acc = __builtin_amdgcn_mfma_f32_16x16x32_bf16(af2[kt], bf[kt], acc, 0, 0, 0);
    #pragma unroll
    for (int r = 0; r < 4; ++r) {
      int ge = geb + mbase + q * 4 + r;
      if (ge < E) edge_out[(size_t)ge * 128 + n] = acc[r];
    }
  }
}

extern "C" void kernel_launch(void* const* d_in, const int* in_sizes, int n_in,
                              void* d_out, int out_size, void* d_ws, size_t ws_size,
                              hipStream_t stream) {
  const float* atom = (const float*)d_in[0];
  const float* el   = (const float*)d_in[1];
  const float* ev   = (const float*)d_in[2];
  const int*   eidx = (const int*)d_in[3];
  const float* aw1  = (const float*)d_in[4];
  const float* ab1  = (const float*)d_in[5];
  const float* ag   = (const float*)d_in[6];
  const float* abn  = (const float*)d_in[7];
  const float* aw2  = (const float*)d_in[8];
  const float* ab2  = (const float*)d_in[9];
  const float* iw1  = (const float*)d_in[10];
  const float* ib1  = (const float*)d_in[11];
  const float* ig   = (const float*)d_in[12];
  const float* ibn  = (const float*)d_in[13];
  const float* iw2  = (const float*)d_in[14];
  const float* ib2  = (const float*)d_in[15];
  const float* mw1  = (const float*)d_in[16];
  const float* mb1  = (const float*)d_in[17];
  const float* mg   = (const float*)d_in[18];
  const float* mbn  = (const float*)d_in[19];
  const float* mw2  = (const float*)d_in[20];
  const float* mb2  = (const float*)d_in[21];

  const int N = in_sizes[0] / 64;
  const int E = in_sizes[1] / 64;
  const int* src = eidx;
  const int* dst = eidx + E;

  char* ws = (char*)d_ws;
  size_t off = 0;
  int* last_idx = (int*)(ws + off);          off += 256;
  unsigned char* rawmask = (unsigned char*)(ws + off); off += ((size_t)E + 255) & ~(size_t)255;
  float* Wfa  = (float*)(ws + off);          off += (size_t)384 * 64 * 4;
  float* cfa  = (float*)(ws + off);          off += 384 * 4;
  float* wg   = (float*)(ws + off);          off += 256;
  float* bg   = (float*)(ws + off);          off += 256;
  float* angp = (float*)(ws + off);          off += 256;
  unsigned short* B1 = (unsigned short*)(ws + off); off += (size_t)24 * 12 * 64 * 8 * 2;
  unsigned short* B2 = (unsigned short*)(ws + off); off += (size_t)8 * 12 * 64 * 8 * 2;
  unsigned short* B3 = (unsigned short*)(ws + off); off += (size_t)8 * 10 * 64 * 8 * 2;
  unsigned short* B4 = (unsigned short*)(ws + off); off += (size_t)8 * 4 * 64 * 8 * 2;

  float* node_out = (float*)d_out;
  float* edge_out = node_out + (size_t)N * 128;

  const int eb = (E + 255) / 256;
  const int tb = (E + 63) / 64;
  const int swz_n = 24 * 12 * 64 + 8 * 12 * 64 + 8 * 10 * 64 + 8 * 4 * 64;

  k_init<<<2048, 256, 0, stream>>>(node_out, N * 128, last_idx);
  k_mask<<<eb, 256, 0, stream>>>(src, dst, E, rawmask, last_idx);
  k_setup<<<(384 * 64 + 384 + 64 + 255) / 256, 256, 0, stream>>>(
      iw1, aw2, ab2, aw1, ab1, ag, Wfa, cfa, wg, bg, angp);
  k_swz<<<(swz_n + 255) / 256, 256, 0, stream>>>(iw1, iw2, mw1, mw2, Wfa, B1, B2, B3, B4);
  k_inv<<<tb, 256, 0, stream>>>(atom, el, ev, src, dst, rawmask, last_idx,
                                ib1, ig, ibn, ib2, cfa, wg, bg, abn, angp,
                                B1, B2, node_out, E);
  k_mrg<<<tb, 256, 0, stream>>>(node_out, el, src, dst,
                                mb1, mg, mbn, mb2, B3, B4, edge_out, E);
}